// Round 4
// baseline (4154.086 us; speedup 1.0000x reference)
//
#include <hip/hip_runtime.h>
#include <stdint.h>

#define B_ 64
#define T_ 2048
#define I_ 256
#define H_ 256
#define G3 768
#define NPROD 192          // producer blocks; 64 + 192 = 256 = CU count (1 block/CU)
#define CH 16              // timesteps per ready-chunk
#define NTILE_N 6          // n-tiles of 128 covering G3=768

typedef _Float16 half2v __attribute__((ext_vector_type(2)));
typedef _Float16 half8v __attribute__((ext_vector_type(8)));

#if __has_builtin(__builtin_amdgcn_fdot2)
#define FDOT2(a, b, c) __builtin_amdgcn_fdot2((a), (b), (c), false)
#else
#define FDOT2(a, b, c) fmaf((float)(a)[1], (float)(b)[1], fmaf((float)(a)[0], (float)(b)[0], (c)))
#endif

// Light barrier: drain LDS ops only (lgkmcnt(0)), leave global loads in flight.
// s_waitcnt imm (gfx9): vmcnt[3:0]+[15:14]=63 (no wait), expcnt[6:4]=7, lgkmcnt[11:8]=0.
#define BAR_LGKM() do {                      \
    __builtin_amdgcn_s_waitcnt(0xC07F);      \
    __builtin_amdgcn_s_barrier();            \
  } while (0)

__global__ void zero_flags(int* __restrict__ done, int n)
{
  int i = threadIdx.x + blockIdx.x * blockDim.x;
  if (i < n) __hip_atomic_store(&done[i], 0, __ATOMIC_RELAXED, __HIP_MEMORY_SCOPE_AGENT);
}

// Round-3 lesson: the consumer step is dominated by LDS h-broadcast RETURN traffic
// (ds_read_b128 delivers 1 KiB per instruction regardless of broadcast). Fix: k-split 4
// (s2 = tid&3 owns k-quarter [64*s2, 64*s2+64)), 2 cells per lane (j0, j0+128), so each
// lane reads 64 halves = 8 b128 -> per-CU LDS return traffic halves vs round 3.
// Reduction over the 4-lane k-group via shfl_xor(1), shfl_xor(2) (DPP).
__global__ __launch_bounds__(512) __attribute__((amdgpu_waves_per_eu(2, 2)))
void fused(const float* __restrict__ x, const float* __restrict__ att,
           const int* __restrict__ lengths, const float* __restrict__ Wih,
           const float* __restrict__ Whh, const float* __restrict__ bih,
           const float* __restrict__ bhh, float* __restrict__ gi,
           int* __restrict__ done, float* __restrict__ hws,
           float* __restrict__ out, int t0, int t1)
{
  __shared__ __align__(16) float smem[32 * 68 + 32 * 132];   // 25600 B, both roles
  const int tid = threadIdx.x;
  const int Tc = t1 - t0;

  if (blockIdx.x >= B_) {
    // ---------------- producer: gi GEMM (unchanged) ----------------
    const int pid = blockIdx.x - B_;
    float* As = smem;               // [32][68]
    float* Bs = smem + 32 * 68;     // [32][132]
    const int ty = tid >> 5, tx = tid & 31;
    const int lr = tid >> 3;
    const int lk = (tid & 7) << 2;
    const int NT = Tc * NTILE_N;
    for (int i = pid; i < NT; i += NPROD) {
      const int rel = i / NTILE_N;          // t - t0 (t-major => early chunks finish first)
      const int tt  = t0 + rel;
      const int n0  = (i % NTILE_N) << 7;
      float acc[4][4] = {};
      for (int kc = 0; kc < I_; kc += 32) {
        float4 a0 = *(const float4*)(x + ((size_t)lr * T_ + tt) * I_ + kc + lk);
        float4 b0 = *(const float4*)(Wih + (size_t)(n0 + lr) * I_ + kc + lk);
        float4 b1 = *(const float4*)(Wih + (size_t)(n0 + lr + 64) * I_ + kc + lk);
        __syncthreads();
        As[(lk + 0) * 68 + lr] = a0.x; As[(lk + 1) * 68 + lr] = a0.y;
        As[(lk + 2) * 68 + lr] = a0.z; As[(lk + 3) * 68 + lr] = a0.w;
        Bs[(lk + 0) * 132 + lr] = b0.x; Bs[(lk + 1) * 132 + lr] = b0.y;
        Bs[(lk + 2) * 132 + lr] = b0.z; Bs[(lk + 3) * 132 + lr] = b0.w;
        Bs[(lk + 0) * 132 + lr + 64] = b1.x; Bs[(lk + 1) * 132 + lr + 64] = b1.y;
        Bs[(lk + 2) * 132 + lr + 64] = b1.z; Bs[(lk + 3) * 132 + lr + 64] = b1.w;
        __syncthreads();
        #pragma unroll
        for (int kk = 0; kk < 32; ++kk) {
          float4 av = *(const float4*)(&As[kk * 68 + (ty << 2)]);
          float4 bv = *(const float4*)(&Bs[kk * 132 + (tx << 2)]);
          float av_[4] = {av.x, av.y, av.z, av.w};
          float bv_[4] = {bv.x, bv.y, bv.z, bv.w};
          #pragma unroll
          for (int u = 0; u < 4; ++u)
            #pragma unroll
            for (int v = 0; v < 4; ++v)
              acc[u][v] = fmaf(av_[u], bv_[v], acc[u][v]);
        }
      }
      const int colb = n0 + (tx << 2);
      float4 bi = *(const float4*)(bih + colb);
      float4 bh = *(const float4*)(bhh + colb);
      float4 badd;
      badd.x = bi.x + (colb + 0 < 512 ? bh.x : 0.f);
      badd.y = bi.y + (colb + 1 < 512 ? bh.y : 0.f);
      badd.z = bi.z + (colb + 2 < 512 ? bh.z : 0.f);
      badd.w = bi.w + (colb + 3 < 512 ? bh.w : 0.f);
      float* gout = gi + (size_t)rel * B_ * G3;
      #pragma unroll
      for (int r = 0; r < 4; ++r) {
        const int bb = (ty << 2) + r;
        float4 o;
        o.x = acc[r][0] + badd.x; o.y = acc[r][1] + badd.y;
        o.z = acc[r][2] + badd.z; o.w = acc[r][3] + badd.w;
        *(float4*)(gout + (size_t)bb * G3 + colb) = o;
      }
      __syncthreads();   // vmcnt(0): all 512 threads' stores drained
      if (tid == 0) {
        __threadfence();
        __hip_atomic_fetch_add(&done[rel >> 4], 1, __ATOMIC_RELEASE, __HIP_MEMORY_SCOPE_AGENT);
      }
    }
    return;
  }

  // ---------------- consumer: per-batch recurrence, k-split 4 ----------------
  const int b  = blockIdx.x;
  const int j0 = tid >> 2;        // cell group: owns cells j0 and j0+128
  const int s2 = tid & 3;         // k-quarter [64*s2, 64*s2+64)
  const int k0 = s2 << 6;
  // hbuf: [2 buffers][4 slices][72 halves] (slice = 64 halves + 8 pad for banks)
  _Float16* hbuf  = (_Float16*)smem;        // 2*288 halves = 1152 B
  float*    att_s = smem + 288;             // Tc floats (<= 8 KiB)

  // W_hh rows -> packed fp16 in registers. 6 cells x 32 half2 = 192 regs.
  // layout: w[(g*2+c)*32 + 2q(+1)] for gate g, cell c (j0 + 128c), k-slice [k0,k0+64)
  half2v w[192];
  #pragma unroll
  for (int g = 0; g < 3; ++g) {
    #pragma unroll
    for (int c = 0; c < 2; ++c) {
      const float* row = Whh + (size_t)(g * 256 + j0 + 128 * c) * H_ + k0;
      const int base = (g * 2 + c) * 32;
      #pragma unroll
      for (int q = 0; q < 16; ++q) {
        float4 v = *(const float4*)(row + (q << 2));
        half2v a, cc;
        a[0]  = (_Float16)v.x; a[1]  = (_Float16)v.y;
        cc[0] = (_Float16)v.z; cc[1] = (_Float16)v.w;
        w[base + 2 * q]     = a;
        w[base + 2 * q + 1] = cc;
      }
    }
  }

  float bhnA = 0.f, bhnB = 0.f, hA = 0.f, hB = 0.f;
  if (s2 == 0) {
    bhnA = bhh[512 + j0];
    bhnB = bhh[512 + 128 + j0];
    if (t0 > 0) { hA = hws[b * H_ + j0]; hB = hws[b * H_ + 128 + j0]; }
  }
  if (tid < 256) {
    float v = (t0 > 0) ? hws[b * H_ + tid] : 0.f;
    hbuf[(tid >> 6) * 72 + (tid & 63)] = (_Float16)v;
  }
  for (int i = tid; i < Tc; i += 512) att_s[i] = att[(size_t)b * T_ + t0 + i];
  int len = lengths[b]; if (len > t1) len = t1;
  const int nch = (Tc + CH - 1) / CH;
  int wm = -1;
  __syncthreads();

#define GATE(NEED) do {                                                               \
    int need_ = (NEED); if (need_ > nch - 1) need_ = nch - 1;                         \
    if (need_ > wm) {                                                                 \
      if (tid == 0) {                                                                 \
        for (int c_ = wm + 1; c_ <= need_; ++c_) {                                    \
          int exp_ = ((Tc - c_ * CH) < CH ? (Tc - c_ * CH) : CH) * NTILE_N;           \
          while (__hip_atomic_load(&done[c_], __ATOMIC_RELAXED,                       \
                                   __HIP_MEMORY_SCOPE_AGENT) < exp_)                  \
            __builtin_amdgcn_s_sleep(2);                                              \
        }                                                                             \
      }                                                                               \
      __syncthreads();                                                                \
      __threadfence();  /* acquire: order flag-read before subsequent gi loads */     \
      wm = need_;                                                                     \
    }                                                                                 \
  } while (0)

  // One step: 8 b128 LDS reads (64 halves), 192 fdot2 over 6 accumulators,
  // 2-round shfl_xor k-reduction, epilogue for 2 cells on s2==0 lanes, then
  // re-issue the same gi register set for TT+3. Light barrier (lgkm only).
#define STEP(GRA, GZA, GNA, GRB, GZB, GNB, TT, ISSUE_OK) do {                         \
    float wat_ = (s2 == 0) ? att_s[(TT) - t0] : 0.f;                                  \
    float arA = 0.f, azA = 0.f, anA = 0.f;                                            \
    float arB = 0.f, azB = 0.f, anB = 0.f;                                            \
    const _Float16* hb = hbuf + p * 288 + s2 * 72;                                    \
    _Pragma("unroll")                                                                 \
    for (int q = 0; q < 8; ++q) {                                                     \
      half8v hv = *(const half8v*)(hb + (q << 3));                                    \
      half2v h0_ = __builtin_shufflevector(hv, hv, 0, 1);                             \
      half2v h1_ = __builtin_shufflevector(hv, hv, 2, 3);                             \
      half2v h2_ = __builtin_shufflevector(hv, hv, 4, 5);                             \
      half2v h3_ = __builtin_shufflevector(hv, hv, 6, 7);                             \
      const int qq = q << 2;                                                          \
      arA = FDOT2(w[qq + 0], h0_, arA);                                               \
      arA = FDOT2(w[qq + 1], h1_, arA);                                               \
      arA = FDOT2(w[qq + 2], h2_, arA);                                               \
      arA = FDOT2(w[qq + 3], h3_, arA);                                               \
      arB = FDOT2(w[32 + qq + 0], h0_, arB);                                          \
      arB = FDOT2(w[32 + qq + 1], h1_, arB);                                          \
      arB = FDOT2(w[32 + qq + 2], h2_, arB);                                          \
      arB = FDOT2(w[32 + qq + 3], h3_, arB);                                          \
      azA = FDOT2(w[64 + qq + 0], h0_, azA);                                          \
      azA = FDOT2(w[64 + qq + 1], h1_, azA);                                          \
      azA = FDOT2(w[64 + qq + 2], h2_, azA);                                          \
      azA = FDOT2(w[64 + qq + 3], h3_, azA);                                          \
      azB = FDOT2(w[96 + qq + 0], h0_, azB);                                          \
      azB = FDOT2(w[96 + qq + 1], h1_, azB);                                          \
      azB = FDOT2(w[96 + qq + 2], h2_, azB);                                          \
      azB = FDOT2(w[96 + qq + 3], h3_, azB);                                          \
      anA = FDOT2(w[128 + qq + 0], h0_, anA);                                         \
      anA = FDOT2(w[128 + qq + 1], h1_, anA);                                         \
      anA = FDOT2(w[128 + qq + 2], h2_, anA);                                         \
      anA = FDOT2(w[128 + qq + 3], h3_, anA);                                         \
      anB = FDOT2(w[160 + qq + 0], h0_, anB);                                         \
      anB = FDOT2(w[160 + qq + 1], h1_, anB);                                         \
      anB = FDOT2(w[160 + qq + 2], h2_, anB);                                         \
      anB = FDOT2(w[160 + qq + 3], h3_, anB);                                         \
    }                                                                                 \
    arA += __shfl_xor(arA, 1); arA += __shfl_xor(arA, 2);                             \
    azA += __shfl_xor(azA, 1); azA += __shfl_xor(azA, 2);                             \
    anA += __shfl_xor(anA, 1); anA += __shfl_xor(anA, 2);                             \
    arB += __shfl_xor(arB, 1); arB += __shfl_xor(arB, 2);                             \
    azB += __shfl_xor(azB, 1); azB += __shfl_xor(azB, 2);                             \
    anB += __shfl_xor(anB, 1); anB += __shfl_xor(anB, 2);                             \
    if (s2 == 0) {                                                                    \
      float rA = 1.f / (1.f + __expf(-(arA + GRA)));                                  \
      float zA = 1.f / (1.f + __expf(-(azA + GZA)));                                  \
      float e2A = __expf(2.f * (GNA + rA * (anA + bhnA)));                            \
      float nnA = 1.f - 2.f / (e2A + 1.f);                                            \
      float hnA = (1.f - zA) * nnA + zA * hA;                                         \
      hA = wat_ * hnA + (1.f - wat_) * hA;                                            \
      float rB = 1.f / (1.f + __expf(-(arB + GRB)));                                  \
      float zB = 1.f / (1.f + __expf(-(azB + GZB)));                                  \
      float e2B = __expf(2.f * (GNB + rB * (anB + bhnB)));                            \
      float nnB = 1.f - 2.f / (e2B + 1.f);                                            \
      float hnB = (1.f - zB) * nnB + zB * hB;                                         \
      hB = wat_ * hnB + (1.f - wat_) * hB;                                            \
      const int pp = (p ^ 1) * 288;                                                   \
      hbuf[pp + (j0 >> 6) * 72 + (j0 & 63)]       = (_Float16)hA;                     \
      hbuf[pp + 144 + (j0 >> 6) * 72 + (j0 & 63)] = (_Float16)hB;                     \
    }                                                                                 \
    if (s2 == 0 && (ISSUE_OK)) {   /* re-issue same regs for TT+3 */                  \
      const float* gb_ = gi + ((size_t)((TT) + 3 - t0) * B_ + b) * G3;                \
      GRA = gb_[j0];       GZA = gb_[256 + j0];       GNA = gb_[512 + j0];            \
      GRB = gb_[128 + j0]; GZB = gb_[384 + j0];       GNB = gb_[640 + j0];            \
    }                                                                                 \
    BAR_LGKM();                                                                       \
    p ^= 1;                                                                           \
  } while (0)

  GATE(0);
  // depth-3 rotating prefetch sets (6 floats each)
  float A_gr = 0.f, A_gz = 0.f, A_gn = 0.f, A_hr = 0.f, A_hz = 0.f, A_hn = 0.f;
  float B_gr = 0.f, B_gz = 0.f, B_gn = 0.f, B_hr = 0.f, B_hz = 0.f, B_hn = 0.f;
  float C_gr = 0.f, C_gz = 0.f, C_gn = 0.f, C_hr = 0.f, C_hz = 0.f, C_hn = 0.f;
  if (s2 == 0 && t0 + 0 < len) {
    const float* gb = gi + ((size_t)0 * B_ + b) * G3;
    A_gr = gb[j0]; A_gz = gb[256 + j0]; A_gn = gb[512 + j0];
    A_hr = gb[128 + j0]; A_hz = gb[384 + j0]; A_hn = gb[640 + j0];
  }
  if (s2 == 0 && t0 + 1 < len) {
    const float* gb = gi + ((size_t)1 * B_ + b) * G3;
    B_gr = gb[j0]; B_gz = gb[256 + j0]; B_gn = gb[512 + j0];
    B_hr = gb[128 + j0]; B_hz = gb[384 + j0]; B_hn = gb[640 + j0];
  }
  if (s2 == 0 && t0 + 2 < len) {
    const float* gb = gi + ((size_t)2 * B_ + b) * G3;
    C_gr = gb[j0]; C_gz = gb[256 + j0]; C_gn = gb[512 + j0];
    C_hr = gb[128 + j0]; C_hz = gb[384 + j0]; C_hn = gb[640 + j0];
  }

  int p = 0;
  int t = t0;
  for (; t + 2 < len; t += 3) {
    GATE((t + 5 - t0) >> 4);
    STEP(A_gr, A_gz, A_gn, A_hr, A_hz, A_hn, t,     (t + 3 < len));
    STEP(B_gr, B_gz, B_gn, B_hr, B_hz, B_hn, t + 1, (t + 4 < len));
    STEP(C_gr, C_gz, C_gn, C_hr, C_hz, C_hn, t + 2, (t + 5 < len));
  }
  if (t < len) { STEP(A_gr, A_gz, A_gn, A_hr, A_hz, A_hn, t, false); ++t; }
  if (t < len) { STEP(B_gr, B_gz, B_gn, B_hr, B_hz, B_hn, t, false); ++t; }

  if (s2 == 0) {
    hws[b * H_ + j0]       = hA;
    hws[b * H_ + 128 + j0] = hB;
    if (t1 == T_) { out[b * H_ + j0] = hA; out[b * H_ + 128 + j0] = hB; }
  }
#undef STEP
#undef GATE
}

extern "C" void kernel_launch(void* const* d_in, const int* in_sizes, int n_in,
                              void* d_out, int out_size, void* d_ws, size_t ws_size,
                              hipStream_t stream)
{
  const float* x       = (const float*)d_in[0];
  const float* att     = (const float*)d_in[1];
  const int*   lengths = (const int*)d_in[2];
  const float* Wih     = (const float*)d_in[3];
  const float* Whh     = (const float*)d_in[4];
  const float* bih     = (const float*)d_in[5];
  const float* bhh     = (const float*)d_in[6];
  float* out = (float*)d_out;

  // workspace layout: [0,4K) chunk flags | [4K, 4K+64K) h carry | gi after
  int*   done = (int*)d_ws;
  float* hws  = (float*)((char*)d_ws + 4096);
  float* gi   = (float*)((char*)d_ws + 4096 + 65536);
  const size_t used0 = 4096 + 65536;
  const size_t per_t = (size_t)B_ * G3 * sizeof(float);
  size_t avail = ws_size > used0 ? ws_size - used0 : 0;
  int Tc = (int)(avail / per_t);
  if (Tc > T_) Tc = T_;
  if (Tc < 1) Tc = 1;

  for (int t0 = 0; t0 < T_; t0 += Tc) {
    int t1 = t0 + Tc; if (t1 > T_) t1 = T_;
    int nch = (t1 - t0 + CH - 1) / CH;
    zero_flags<<<dim3((nch + 127) / 128), 128, 0, stream>>>(done, nch);
    fused<<<dim3(B_ + NPROD), 512, 0, stream>>>(x, att, lengths, Wih, Whh, bih, bhh,
                                                gi, done, hws, out, t0, t1);
  }
}

// Round 5
// 3851.715 us; speedup vs baseline: 1.0785x; 1.0785x over previous
//
#include <hip/hip_runtime.h>
#include <stdint.h>

#define B_ 64
#define T_ 2048
#define I_ 256
#define H_ 256
#define G3 768
#define NPROD 192          // producer blocks; 64 + 192 = 256 = CU count (1 block/CU)
#define CH 16              // timesteps per ready-chunk
#define NTILE_N 6          // n-tiles of 128 covering G3=768
#define LEADW 192          // producer max lead over slowest consumer (timesteps); 36 MB < L3

typedef _Float16 half2v __attribute__((ext_vector_type(2)));
typedef _Float16 half8v __attribute__((ext_vector_type(8)));

#if __has_builtin(__builtin_amdgcn_fdot2)
#define FDOT2(a, b, c) __builtin_amdgcn_fdot2((a), (b), (c), false)
#else
#define FDOT2(a, b, c) fmaf((float)(a)[1], (float)(b)[1], fmaf((float)(a)[0], (float)(b)[0], (c)))
#endif

__global__ void zero_flags(int* __restrict__ done, int n)
{
  int i = threadIdx.x + blockIdx.x * blockDim.x;
  if (i < n) __hip_atomic_store(&done[i], 0, __ATOMIC_RELAXED, __HIP_MEMORY_SCOPE_AGENT);
}

// Round-4 lesson: fused-kernel slowdown was L3 eviction -- the unthrottled producer ran
// ~full-sequence ahead (380 MB gi + 128 MB x streamed through the 256 MB L3), so ALL
// consumer gi reads became HBM misses (FETCH 118->516 MB). Fix: producers stay <= LEADW
// timesteps ahead of the slowest consumer (progress published in prog[], wave-0 spin
// with shfl-min). Consumer = verbatim round-0 step (proven 3100 cy/step): depth-1
// prefetch issued at step TOP, full __syncthreads per step.
__global__ __launch_bounds__(512) __attribute__((amdgpu_waves_per_eu(2, 2)))
void fused(const float* __restrict__ x, const float* __restrict__ att,
           const int* __restrict__ lengths, const float* __restrict__ Wih,
           const float* __restrict__ Whh, const float* __restrict__ bih,
           const float* __restrict__ bhh, float* __restrict__ gi,
           int* __restrict__ done, float* __restrict__ hws,
           float* __restrict__ out, int t0, int t1)
{
  __shared__ __align__(16) float smem[32 * 68 + 32 * 132];   // 25600 B, both roles
  const int tid = threadIdx.x;
  const int Tc = t1 - t0;
  int* const prog = done + 128;     // per-consumer progress (steps completed, rel to t0)

  if (blockIdx.x >= B_) {
    // ---------------- producer: gi GEMM, throttled ----------------
    const int pid = blockIdx.x - B_;
    float* As = smem;               // [32][68]
    float* Bs = smem + 32 * 68;     // [32][132]
    const int ty = tid >> 5, tx = tid & 31;
    const int lr = tid >> 3;
    const int lk = (tid & 7) << 2;
    const int NT = Tc * NTILE_N;
    for (int i = pid; i < NT; i += NPROD) {
      const int rel = i / NTILE_N;          // t - t0 (t-major => early chunks finish first)
      const int tt  = t0 + rel;
      const int n0  = (i % NTILE_N) << 7;

      // Throttle: wave 0 spins until rel < min(prog) + LEADW. No barrier inside the
      // spin; one __syncthreads after (all threads execute the same barrier count).
      if (tid < 64) {
        for (;;) {
          int pv = __hip_atomic_load(&prog[tid], __ATOMIC_RELAXED, __HIP_MEMORY_SCOPE_AGENT);
          int m = pv;
          m = min(m, __shfl_xor(m, 32));
          m = min(m, __shfl_xor(m, 16));
          m = min(m, __shfl_xor(m, 8));
          m = min(m, __shfl_xor(m, 4));
          m = min(m, __shfl_xor(m, 2));
          m = min(m, __shfl_xor(m, 1));
          if (rel < m + LEADW) break;
          __builtin_amdgcn_s_sleep(8);
        }
      }
      __syncthreads();

      float acc[4][4] = {};
      for (int kc = 0; kc < I_; kc += 32) {
        float4 a0 = *(const float4*)(x + ((size_t)lr * T_ + tt) * I_ + kc + lk);
        float4 b0 = *(const float4*)(Wih + (size_t)(n0 + lr) * I_ + kc + lk);
        float4 b1 = *(const float4*)(Wih + (size_t)(n0 + lr + 64) * I_ + kc + lk);
        __syncthreads();
        As[(lk + 0) * 68 + lr] = a0.x; As[(lk + 1) * 68 + lr] = a0.y;
        As[(lk + 2) * 68 + lr] = a0.z; As[(lk + 3) * 68 + lr] = a0.w;
        Bs[(lk + 0) * 132 + lr] = b0.x; Bs[(lk + 1) * 132 + lr] = b0.y;
        Bs[(lk + 2) * 132 + lr] = b0.z; Bs[(lk + 3) * 132 + lr] = b0.w;
        Bs[(lk + 0) * 132 + lr + 64] = b1.x; Bs[(lk + 1) * 132 + lr + 64] = b1.y;
        Bs[(lk + 2) * 132 + lr + 64] = b1.z; Bs[(lk + 3) * 132 + lr + 64] = b1.w;
        __syncthreads();
        #pragma unroll
        for (int kk = 0; kk < 32; ++kk) {
          float4 av = *(const float4*)(&As[kk * 68 + (ty << 2)]);
          float4 bv = *(const float4*)(&Bs[kk * 132 + (tx << 2)]);
          float av_[4] = {av.x, av.y, av.z, av.w};
          float bv_[4] = {bv.x, bv.y, bv.z, bv.w};
          #pragma unroll
          for (int u = 0; u < 4; ++u)
            #pragma unroll
            for (int v = 0; v < 4; ++v)
              acc[u][v] = fmaf(av_[u], bv_[v], acc[u][v]);
        }
      }
      const int colb = n0 + (tx << 2);
      float4 bi = *(const float4*)(bih + colb);
      float4 bh = *(const float4*)(bhh + colb);
      float4 badd;
      badd.x = bi.x + (colb + 0 < 512 ? bh.x : 0.f);
      badd.y = bi.y + (colb + 1 < 512 ? bh.y : 0.f);
      badd.z = bi.z + (colb + 2 < 512 ? bh.z : 0.f);
      badd.w = bi.w + (colb + 3 < 512 ? bh.w : 0.f);
      float* gout = gi + (size_t)rel * B_ * G3;
      #pragma unroll
      for (int r = 0; r < 4; ++r) {
        const int bb = (ty << 2) + r;
        float4 o;
        o.x = acc[r][0] + badd.x; o.y = acc[r][1] + badd.y;
        o.z = acc[r][2] + badd.z; o.w = acc[r][3] + badd.w;
        *(float4*)(gout + (size_t)bb * G3 + colb) = o;
      }
      __syncthreads();   // vmcnt(0): all 512 threads' stores drained
      if (tid == 0) {
        __threadfence();
        __hip_atomic_fetch_add(&done[rel >> 4], 1, __ATOMIC_RELEASE, __HIP_MEMORY_SCOPE_AGENT);
      }
    }
    return;
  }

  // ---------------- consumer: per-batch recurrence (round-0 structure) ----------------
  const int b  = blockIdx.x;
  const int j  = tid >> 1;
  const int s  = tid & 1;
  const int k0 = s << 7;
  _Float16* hbuf = (_Float16*)smem;   // [2][272] halves, slice stride 136

  // W_hh rows -> packed fp16 in registers (prologue only)
  half2v w[192];
  #pragma unroll
  for (int g = 0; g < 3; ++g) {
    const float* row = Whh + (size_t)(g * 256 + j) * H_ + k0;
    #pragma unroll
    for (int q = 0; q < 32; ++q) {
      float4 v = *(const float4*)(row + (q << 2));
      half2v a, c;
      a[0] = (_Float16)v.x; a[1] = (_Float16)v.y;
      c[0] = (_Float16)v.z; c[1] = (_Float16)v.w;
      w[g * 64 + 2 * q]     = a;
      w[g * 64 + 2 * q + 1] = c;
    }
  }

  float bhn = 0.f, h_reg = 0.f;
  if (s == 0) {
    bhn = bhh[512 + j];
    h_reg = (t0 > 0) ? hws[b * H_ + j] : 0.f;
  }
  if (tid < 256) {
    float v = (t0 > 0) ? hws[b * H_ + tid] : 0.f;
    hbuf[(tid >> 7) * 136 + (tid & 127)] = (_Float16)v;
  }
  int len = lengths[b]; if (len > t1) len = t1;
  const int nch = (Tc + CH - 1) / CH;
  int wm = -1;   // highest chunk known ready
  __syncthreads();

  // Gate (cheap when not crossing): publish progress, then wait for chunks <= NEED.
#define GATE(NEED, TCUR) do {                                                         \
    int need_ = (NEED); if (need_ > nch - 1) need_ = nch - 1;                         \
    if (need_ > wm) {                                                                 \
      if (tid == 0) {                                                                 \
        __hip_atomic_store(&prog[b], (TCUR) - t0, __ATOMIC_RELAXED,                   \
                           __HIP_MEMORY_SCOPE_AGENT);                                 \
        for (int c_ = wm + 1; c_ <= need_; ++c_) {                                    \
          int exp_ = ((Tc - c_ * CH) < CH ? (Tc - c_ * CH) : CH) * NTILE_N;           \
          while (__hip_atomic_load(&done[c_], __ATOMIC_RELAXED,                       \
                                   __HIP_MEMORY_SCOPE_AGENT) < exp_)                  \
            __builtin_amdgcn_s_sleep(2);                                              \
        }                                                                             \
      }                                                                               \
      __syncthreads();                                                                \
      __threadfence();  /* acquire: order flag-read before subsequent gi loads */     \
      wm = need_;                                                                     \
    }                                                                                 \
  } while (0)

  // gi/att pipeline (one step ahead), leader lanes (s==0) -- round-0 verbatim
  GATE(0, t0);
  float c_gr = 0.f, c_gz = 0.f, c_gn = 0.f, c_wat = 0.f;
  if (s == 0 && t0 < len) {
    const float* gb = gi + (size_t)b * G3;
    c_gr = gb[j]; c_gz = gb[256 + j]; c_gn = gb[512 + j];
    c_wat = att[(size_t)b * T_ + t0];
  }

  int p = 0;
  for (int t = t0; t < len; ++t) {
    GATE((t + 1 - t0) >> 4, t);
    float n_gr = 0.f, n_gz = 0.f, n_gn = 0.f, n_wat = 0.f;
    if (s == 0 && t + 1 < len) {
      const float* gb = gi + ((size_t)(t + 1 - t0) * B_ + b) * G3;
      n_gr = gb[j]; n_gz = gb[256 + j]; n_gn = gb[512 + j];
      n_wat = att[(size_t)b * T_ + t + 1];
    }

    float accr = 0.f, accz = 0.f, accn = 0.f;
    const _Float16* hb = hbuf + p * 272 + s * 136;
    #pragma unroll
    for (int q = 0; q < 16; ++q) {
      half8v hv = *(const half8v*)(hb + (q << 3));
      half2v h0 = __builtin_shufflevector(hv, hv, 0, 1);
      half2v h1 = __builtin_shufflevector(hv, hv, 2, 3);
      half2v h2 = __builtin_shufflevector(hv, hv, 4, 5);
      half2v h3 = __builtin_shufflevector(hv, hv, 6, 7);
      const int qq = q << 2;
      accr = FDOT2(w[qq + 0], h0, accr);
      accr = FDOT2(w[qq + 1], h1, accr);
      accr = FDOT2(w[qq + 2], h2, accr);
      accr = FDOT2(w[qq + 3], h3, accr);
      accz = FDOT2(w[64 + qq + 0], h0, accz);
      accz = FDOT2(w[64 + qq + 1], h1, accz);
      accz = FDOT2(w[64 + qq + 2], h2, accz);
      accz = FDOT2(w[64 + qq + 3], h3, accz);
      accn = FDOT2(w[128 + qq + 0], h0, accn);
      accn = FDOT2(w[128 + qq + 1], h1, accn);
      accn = FDOT2(w[128 + qq + 2], h2, accn);
      accn = FDOT2(w[128 + qq + 3], h3, accn);
    }
    // reduce over the 2 k-halves (adjacent lanes)
    accr += __shfl_xor(accr, 1);
    accz += __shfl_xor(accz, 1);
    accn += __shfl_xor(accn, 1);

    if (s == 0) {
      float r = 1.f / (1.f + __expf(-(accr + c_gr)));
      float z = 1.f / (1.f + __expf(-(accz + c_gz)));
      float e2 = __expf(2.f * (c_gn + r * (accn + bhn)));
      float nn = 1.f - 2.f / (e2 + 1.f);      // tanh
      float hnew = (1.f - z) * nn + z * h_reg;
      h_reg = c_wat * hnew + (1.f - c_wat) * h_reg;
      hbuf[(p ^ 1) * 272 + (j >> 7) * 136 + (j & 127)] = (_Float16)h_reg;
    }
    __syncthreads();
    p ^= 1;
    c_gr = n_gr; c_gz = n_gz; c_gn = n_gn; c_wat = n_wat;
  }

  if (tid == 0) {
    __hip_atomic_store(&prog[b], Tc, __ATOMIC_RELAXED, __HIP_MEMORY_SCOPE_AGENT);
  }
  if (s == 0) {
    hws[b * H_ + j] = h_reg;
    if (t1 == T_) out[b * H_ + j] = h_reg;
  }
#undef GATE
}

extern "C" void kernel_launch(void* const* d_in, const int* in_sizes, int n_in,
                              void* d_out, int out_size, void* d_ws, size_t ws_size,
                              hipStream_t stream)
{
  const float* x       = (const float*)d_in[0];
  const float* att     = (const float*)d_in[1];
  const int*   lengths = (const int*)d_in[2];
  const float* Wih     = (const float*)d_in[3];
  const float* Whh     = (const float*)d_in[4];
  const float* bih     = (const float*)d_in[5];
  const float* bhh     = (const float*)d_in[6];
  float* out = (float*)d_out;

  // workspace: [0,512) done flags (128) | [512,768) prog (64) | pad to 4K | h carry | gi
  int*   done = (int*)d_ws;
  float* hws  = (float*)((char*)d_ws + 4096);
  float* gi   = (float*)((char*)d_ws + 4096 + 65536);
  const size_t used0 = 4096 + 65536;
  const size_t per_t = (size_t)B_ * G3 * sizeof(float);
  size_t avail = ws_size > used0 ? ws_size - used0 : 0;
  int Tc = (int)(avail / per_t);
  if (Tc > T_) Tc = T_;
  if (Tc < 1) Tc = 1;

  for (int t0 = 0; t0 < T_; t0 += Tc) {
    int t1 = t0 + Tc; if (t1 > T_) t1 = T_;
    int nch = (t1 - t0 + CH - 1) / CH;
    int nflags = 128 + B_;                 // done[128] + prog[64]
    (void)nch;
    zero_flags<<<dim3((nflags + 127) / 128), 128, 0, stream>>>(done, nflags);
    fused<<<dim3(B_ + NPROD), 512, 0, stream>>>(x, att, lengths, Wih, Whh, bih, bhh,
                                                gi, done, hws, out, t0, t1);
  }
}

// Round 6
// 3669.564 us; speedup vs baseline: 1.1320x; 1.0496x over previous
//
#include <hip/hip_runtime.h>
#include <stdint.h>

#define B_ 64
#define T_ 2048
#define I_ 256
#define H_ 256
#define G3 768
#define NPROD 96           // producer blocks; 64+96=160 CUs busy, 96 idle (clock headroom).
                           // Rate: 96 blocks / 15.8 us/tile = 6.1 tiles/us > consumer 4.3.
#define CH 16              // timesteps per ready-chunk
#define NTILE_N 6          // n-tiles of 128 covering G3=768
#define LEADW 128          // producer max lead over slowest consumer (24 MB gi window)

typedef _Float16 half2v __attribute__((ext_vector_type(2)));
typedef _Float16 half8v __attribute__((ext_vector_type(8)));

#if __has_builtin(__builtin_amdgcn_fdot2)
#define FDOT2(a, b, c) __builtin_amdgcn_fdot2((a), (b), (c), false)
#else
#define FDOT2(a, b, c) fmaf((float)(a)[1], (float)(b)[1], fmaf((float)(a)[0], (float)(b)[0], (c)))
#endif

__global__ void zero_flags(int* __restrict__ done, int n)
{
  int i = threadIdx.x + blockIdx.x * blockDim.x;
  if (i < n) __hip_atomic_store(&done[i], 0, __ATOMIC_RELAXED, __HIP_MEMORY_SCOPE_AGENT);
}

// Rounds 1-5 lesson: fused consumer step time (4100-4400 cy) is INSENSITIVE to prefetch
// depth, barrier type, LDS traffic, and producer lead -> the adder vs unfused (3100 cy)
// is a chip-global rate effect (clock throttle from 256 busy CUs and/or fabric
// contention), not per-load latency. This round: NPROD 192->96 (96 CUs idle -> boost
// clock; halved producer fabric traffic), gentler throttle polling (s_sleep(16)).
// Consumer = verbatim round-0 structure (proven 3100 cy/step).
__global__ __launch_bounds__(512) __attribute__((amdgpu_waves_per_eu(2, 2)))
void fused(const float* __restrict__ x, const float* __restrict__ att,
           const int* __restrict__ lengths, const float* __restrict__ Wih,
           const float* __restrict__ Whh, const float* __restrict__ bih,
           const float* __restrict__ bhh, float* __restrict__ gi,
           int* __restrict__ done, float* __restrict__ hws,
           float* __restrict__ out, int t0, int t1)
{
  __shared__ __align__(16) float smem[32 * 68 + 32 * 132];   // 25600 B, both roles
  const int tid = threadIdx.x;
  const int Tc = t1 - t0;
  int* const prog = done + 128;     // per-consumer progress (steps completed, rel to t0)

  if (blockIdx.x >= B_) {
    // ---------------- producer: gi GEMM, throttled ----------------
    const int pid = blockIdx.x - B_;
    float* As = smem;               // [32][68]
    float* Bs = smem + 32 * 68;     // [32][132]
    const int ty = tid >> 5, tx = tid & 31;
    const int lr = tid >> 3;
    const int lk = (tid & 7) << 2;
    const int NT = Tc * NTILE_N;
    for (int i = pid; i < NT; i += NPROD) {
      const int rel = i / NTILE_N;          // t - t0 (t-major => early chunks finish first)
      const int tt  = t0 + rel;
      const int n0  = (i % NTILE_N) << 7;

      // Throttle: wave 0 spins until rel < min(prog) + LEADW. s_sleep(16) ~ 1024 cy
      // between polls (tile takes ~15.8 us, so polling cost/traffic is negligible).
      if (tid < 64) {
        for (;;) {
          int pv = __hip_atomic_load(&prog[tid], __ATOMIC_RELAXED, __HIP_MEMORY_SCOPE_AGENT);
          int m = pv;
          m = min(m, __shfl_xor(m, 32));
          m = min(m, __shfl_xor(m, 16));
          m = min(m, __shfl_xor(m, 8));
          m = min(m, __shfl_xor(m, 4));
          m = min(m, __shfl_xor(m, 2));
          m = min(m, __shfl_xor(m, 1));
          if (rel < m + LEADW) break;
          __builtin_amdgcn_s_sleep(16);
        }
      }
      __syncthreads();

      float acc[4][4] = {};
      for (int kc = 0; kc < I_; kc += 32) {
        float4 a0 = *(const float4*)(x + ((size_t)lr * T_ + tt) * I_ + kc + lk);
        float4 b0 = *(const float4*)(Wih + (size_t)(n0 + lr) * I_ + kc + lk);
        float4 b1 = *(const float4*)(Wih + (size_t)(n0 + lr + 64) * I_ + kc + lk);
        __syncthreads();
        As[(lk + 0) * 68 + lr] = a0.x; As[(lk + 1) * 68 + lr] = a0.y;
        As[(lk + 2) * 68 + lr] = a0.z; As[(lk + 3) * 68 + lr] = a0.w;
        Bs[(lk + 0) * 132 + lr] = b0.x; Bs[(lk + 1) * 132 + lr] = b0.y;
        Bs[(lk + 2) * 132 + lr] = b0.z; Bs[(lk + 3) * 132 + lr] = b0.w;
        Bs[(lk + 0) * 132 + lr + 64] = b1.x; Bs[(lk + 1) * 132 + lr + 64] = b1.y;
        Bs[(lk + 2) * 132 + lr + 64] = b1.z; Bs[(lk + 3) * 132 + lr + 64] = b1.w;
        __syncthreads();
        #pragma unroll
        for (int kk = 0; kk < 32; ++kk) {
          float4 av = *(const float4*)(&As[kk * 68 + (ty << 2)]);
          float4 bv = *(const float4*)(&Bs[kk * 132 + (tx << 2)]);
          float av_[4] = {av.x, av.y, av.z, av.w};
          float bv_[4] = {bv.x, bv.y, bv.z, bv.w};
          #pragma unroll
          for (int u = 0; u < 4; ++u)
            #pragma unroll
            for (int v = 0; v < 4; ++v)
              acc[u][v] = fmaf(av_[u], bv_[v], acc[u][v]);
        }
      }
      const int colb = n0 + (tx << 2);
      float4 bi = *(const float4*)(bih + colb);
      float4 bh = *(const float4*)(bhh + colb);
      float4 badd;
      badd.x = bi.x + (colb + 0 < 512 ? bh.x : 0.f);
      badd.y = bi.y + (colb + 1 < 512 ? bh.y : 0.f);
      badd.z = bi.z + (colb + 2 < 512 ? bh.z : 0.f);
      badd.w = bi.w + (colb + 3 < 512 ? bh.w : 0.f);
      float* gout = gi + (size_t)rel * B_ * G3;
      #pragma unroll
      for (int r = 0; r < 4; ++r) {
        const int bb = (ty << 2) + r;
        float4 o;
        o.x = acc[r][0] + badd.x; o.y = acc[r][1] + badd.y;
        o.z = acc[r][2] + badd.z; o.w = acc[r][3] + badd.w;
        *(float4*)(gout + (size_t)bb * G3 + colb) = o;
      }
      __syncthreads();   // vmcnt(0): all 512 threads' stores drained
      if (tid == 0) {
        __threadfence();
        __hip_atomic_fetch_add(&done[rel >> 4], 1, __ATOMIC_RELEASE, __HIP_MEMORY_SCOPE_AGENT);
      }
    }
    return;
  }

  // ---------------- consumer: per-batch recurrence (round-0 structure) ----------------
  const int b  = blockIdx.x;
  const int j  = tid >> 1;
  const int s  = tid & 1;
  const int k0 = s << 7;
  _Float16* hbuf = (_Float16*)smem;   // [2][272] halves, slice stride 136

  // W_hh rows -> packed fp16 in registers (prologue only)
  half2v w[192];
  #pragma unroll
  for (int g = 0; g < 3; ++g) {
    const float* row = Whh + (size_t)(g * 256 + j) * H_ + k0;
    #pragma unroll
    for (int q = 0; q < 32; ++q) {
      float4 v = *(const float4*)(row + (q << 2));
      half2v a, c;
      a[0] = (_Float16)v.x; a[1] = (_Float16)v.y;
      c[0] = (_Float16)v.z; c[1] = (_Float16)v.w;
      w[g * 64 + 2 * q]     = a;
      w[g * 64 + 2 * q + 1] = c;
    }
  }

  float bhn = 0.f, h_reg = 0.f;
  if (s == 0) {
    bhn = bhh[512 + j];
    h_reg = (t0 > 0) ? hws[b * H_ + j] : 0.f;
  }
  if (tid < 256) {
    float v = (t0 > 0) ? hws[b * H_ + tid] : 0.f;
    hbuf[(tid >> 7) * 136 + (tid & 127)] = (_Float16)v;
  }
  int len = lengths[b]; if (len > t1) len = t1;
  const int nch = (Tc + CH - 1) / CH;
  int wm = -1;   // highest chunk known ready
  __syncthreads();

  // Gate (cheap when not crossing): publish progress, then wait for chunks <= NEED.
#define GATE(NEED, TCUR) do {                                                         \
    int need_ = (NEED); if (need_ > nch - 1) need_ = nch - 1;                         \
    if (need_ > wm) {                                                                 \
      if (tid == 0) {                                                                 \
        __hip_atomic_store(&prog[b], (TCUR) - t0, __ATOMIC_RELAXED,                   \
                           __HIP_MEMORY_SCOPE_AGENT);                                 \
        for (int c_ = wm + 1; c_ <= need_; ++c_) {                                    \
          int exp_ = ((Tc - c_ * CH) < CH ? (Tc - c_ * CH) : CH) * NTILE_N;           \
          while (__hip_atomic_load(&done[c_], __ATOMIC_RELAXED,                       \
                                   __HIP_MEMORY_SCOPE_AGENT) < exp_)                  \
            __builtin_amdgcn_s_sleep(2);                                              \
        }                                                                             \
      }                                                                               \
      __syncthreads();                                                                \
      __threadfence();  /* acquire: order flag-read before subsequent gi loads */     \
      wm = need_;                                                                     \
    }                                                                                 \
  } while (0)

  // gi/att pipeline (one step ahead), leader lanes (s==0) -- round-0 verbatim
  GATE(0, t0);
  float c_gr = 0.f, c_gz = 0.f, c_gn = 0.f, c_wat = 0.f;
  if (s == 0 && t0 < len) {
    const float* gb = gi + (size_t)b * G3;
    c_gr = gb[j]; c_gz = gb[256 + j]; c_gn = gb[512 + j];
    c_wat = att[(size_t)b * T_ + t0];
  }

  int p = 0;
  for (int t = t0; t < len; ++t) {
    GATE((t + 1 - t0) >> 4, t);
    float n_gr = 0.f, n_gz = 0.f, n_gn = 0.f, n_wat = 0.f;
    if (s == 0 && t + 1 < len) {
      const float* gb = gi + ((size_t)(t + 1 - t0) * B_ + b) * G3;
      n_gr = gb[j]; n_gz = gb[256 + j]; n_gn = gb[512 + j];
      n_wat = att[(size_t)b * T_ + t + 1];
    }

    float accr = 0.f, accz = 0.f, accn = 0.f;
    const _Float16* hb = hbuf + p * 272 + s * 136;
    #pragma unroll
    for (int q = 0; q < 16; ++q) {
      half8v hv = *(const half8v*)(hb + (q << 3));
      half2v h0 = __builtin_shufflevector(hv, hv, 0, 1);
      half2v h1 = __builtin_shufflevector(hv, hv, 2, 3);
      half2v h2 = __builtin_shufflevector(hv, hv, 4, 5);
      half2v h3 = __builtin_shufflevector(hv, hv, 6, 7);
      const int qq = q << 2;
      accr = FDOT2(w[qq + 0], h0, accr);
      accr = FDOT2(w[qq + 1], h1, accr);
      accr = FDOT2(w[qq + 2], h2, accr);
      accr = FDOT2(w[qq + 3], h3, accr);
      accz = FDOT2(w[64 + qq + 0], h0, accz);
      accz = FDOT2(w[64 + qq + 1], h1, accz);
      accz = FDOT2(w[64 + qq + 2], h2, accz);
      accz = FDOT2(w[64 + qq + 3], h3, accz);
      accn = FDOT2(w[128 + qq + 0], h0, accn);
      accn = FDOT2(w[128 + qq + 1], h1, accn);
      accn = FDOT2(w[128 + qq + 2], h2, accn);
      accn = FDOT2(w[128 + qq + 3], h3, accn);
    }
    // reduce over the 2 k-halves (adjacent lanes)
    accr += __shfl_xor(accr, 1);
    accz += __shfl_xor(accz, 1);
    accn += __shfl_xor(accn, 1);

    if (s == 0) {
      float r = 1.f / (1.f + __expf(-(accr + c_gr)));
      float z = 1.f / (1.f + __expf(-(accz + c_gz)));
      float e2 = __expf(2.f * (c_gn + r * (accn + bhn)));
      float nn = 1.f - 2.f / (e2 + 1.f);      // tanh
      float hnew = (1.f - z) * nn + z * h_reg;
      h_reg = c_wat * hnew + (1.f - c_wat) * h_reg;
      hbuf[(p ^ 1) * 272 + (j >> 7) * 136 + (j & 127)] = (_Float16)h_reg;
    }
    __syncthreads();
    p ^= 1;
    c_gr = n_gr; c_gz = n_gz; c_gn = n_gn; c_wat = n_wat;
  }

  if (tid == 0) {
    __hip_atomic_store(&prog[b], Tc, __ATOMIC_RELAXED, __HIP_MEMORY_SCOPE_AGENT);
  }
  if (s == 0) {
    hws[b * H_ + j] = h_reg;
    if (t1 == T_) out[b * H_ + j] = h_reg;
  }
#undef GATE
}

extern "C" void kernel_launch(void* const* d_in, const int* in_sizes, int n_in,
                              void* d_out, int out_size, void* d_ws, size_t ws_size,
                              hipStream_t stream)
{
  const float* x       = (const float*)d_in[0];
  const float* att     = (const float*)d_in[1];
  const int*   lengths = (const int*)d_in[2];
  const float* Wih     = (const float*)d_in[3];
  const float* Whh     = (const float*)d_in[4];
  const float* bih     = (const float*)d_in[5];
  const float* bhh     = (const float*)d_in[6];
  float* out = (float*)d_out;

  // workspace: [0,512) done flags (128) | [512,768) prog (64) | pad to 4K | h carry | gi
  int*   done = (int*)d_ws;
  float* hws  = (float*)((char*)d_ws + 4096);
  float* gi   = (float*)((char*)d_ws + 4096 + 65536);
  const size_t used0 = 4096 + 65536;
  const size_t per_t = (size_t)B_ * G3 * sizeof(float);
  size_t avail = ws_size > used0 ? ws_size - used0 : 0;
  int Tc = (int)(avail / per_t);
  if (Tc > T_) Tc = T_;
  if (Tc < 1) Tc = 1;

  for (int t0 = 0; t0 < T_; t0 += Tc) {
    int t1 = t0 + Tc; if (t1 > T_) t1 = T_;
    int nflags = 128 + B_;                 // done[128] + prog[64]
    zero_flags<<<dim3((nflags + 127) / 128), 128, 0, stream>>>(done, nflags);
    fused<<<dim3(B_ + NPROD), 512, 0, stream>>>(x, att, lengths, Wih, Whh, bih, bhh,
                                                gi, done, hws, out, t0, t1);
  }
}